// Round 13
// baseline (309.119 us; speedup 1.0000x reference)
//
#include <hip/hip_runtime.h>
#include <hip/hip_bf16.h>

typedef _Float16 f16x8 __attribute__((ext_vector_type(8)));
typedef _Float16 f16x4 __attribute__((ext_vector_type(4)));
typedef float    f32x4 __attribute__((ext_vector_type(4)));

constexpr int BB = 4;
constexpr int CH = 128;
constexpr int PC = 64;
constexpr int NN = 4096;

constexpr size_t XBUF_BYTES = (size_t)BB * NN * PC * sizeof(_Float16); // 2 MB
constexpr size_t SQ_BYTES   = (size_t)BB * NN * sizeof(float);         // 64 KB

// ---------------------------------------------------------------------------
// ONE kernel, work-queue scheduled (r12 showed gram steady-state = write
// floor; the 31 us of fixed overhead was proj launch + bubble + ramp).
// Items via atomic counter (execution-order handout -> deadlock-free):
//   item 0..1023            : pos-proj (r8 body)  -> xbuf, sq; release posdone
//   item 1024..4095, t=i-1024, g=t/3, p=t%3:
//     p<2  -> gram unit 2g+p (r8 body, at-floor steady state), gated on
//             posdone==1024 (acquire fence invalidates reader L2; writer
//             fence wrote back to shared MALL -> first-call safe)
//     p==2 -> val-proj unit g (r8 body) -- interleaved 2:1 with gram so its
//             8 MB shares the BW stream instead of serializing
// ---------------------------------------------------------------------------
__global__ __launch_bounds__(256) void mega_kernel(
    const float* __restrict__ pos_bot,  // [B,64,N]
    const float* __restrict__ corr,     // [B,128,N]
    const float* __restrict__ Wp,       // [64,64]
    const float* __restrict__ bp,       // [64]
    const float* __restrict__ Wv,       // [128,128]
    const float* __restrict__ bv,       // [128]
    const float* __restrict__ beta,     // [1]
    _Float16*    __restrict__ xbuf,     // [B,N,64]
    float*       __restrict__ sq,       // [B,N]
    float*       __restrict__ eqF,      // [B,N,128]
    float*       __restrict__ out,      // [B,N,N]
    unsigned int* __restrict__ flags)   // [0]=work counter, [1]=posdone
{
    __shared__ int   s_item;
    __shared__ float psum[4][16];
    __shared__ float ldsT[4][16][132];

    const int tid  = threadIdx.x;
    const int wid  = tid >> 6;
    const int lane = tid & 63;
    const int l15  = lane & 15;
    const int lg   = lane >> 4;

    if (tid == 0) s_item = (int)atomicAdd(&flags[0], 1u);
    __syncthreads();
    const int item = s_item;

    if (item < 1024) {
        // ---- pos projection: x~ = f16(Wp @ pos_bot + bp), sq = ||x~||^2 ----
        const int b  = item >> 8;
        const int px = item & 255;
        const int n  = px * 16 + l15;
        const int mt = wid;

        f16x8 wf[2], pb[2];
#pragma unroll
        for (int ks = 0; ks < 2; ++ks) {
            const float* wp = Wp + (mt * 16 + l15) * PC + ks * 32 + lg * 8;
            f32x4 w0 = *reinterpret_cast<const f32x4*>(wp);
            f32x4 w1 = *reinterpret_cast<const f32x4*>(wp + 4);
            f16x8 f;
#pragma unroll
            for (int e = 0; e < 4; ++e) { f[e] = (_Float16)w0[e]; f[e + 4] = (_Float16)w1[e]; }
            wf[ks] = f;
            f16x8 g;
#pragma unroll
            for (int e = 0; e < 8; ++e) {
                const int c = ks * 32 + lg * 8 + e;
                g[e] = (_Float16)pos_bot[((size_t)(b * PC + c)) * NN + n];
            }
            pb[ks] = g;
        }

        f32x4 acc = {0.f, 0.f, 0.f, 0.f};
        acc = __builtin_amdgcn_mfma_f32_16x16x32_f16(wf[0], pb[0], acc, 0, 0, 0);
        acc = __builtin_amdgcn_mfma_f32_16x16x32_f16(wf[1], pb[1], acc, 0, 0, 0);

        float partial = 0.f;
        f16x4 h4;
#pragma unroll
        for (int r = 0; r < 4; ++r) {
            const int o = mt * 16 + lg * 4 + r;
            const float v = acc[r] + bp[o];
            const _Float16 h = (_Float16)v;
            h4[r] = h;
            const float hf = (float)h;
            partial = fmaf(hf, hf, partial);
        }
        *reinterpret_cast<f16x4*>(xbuf + ((size_t)(b * NN + n)) * PC + mt * 16 + lg * 4) = h4;

        partial += __shfl_xor(partial, 16);
        partial += __shfl_xor(partial, 32);
        if (lane < 16) psum[wid][l15] = partial;
        __syncthreads();
        if (tid < 16)
            sq[b * NN + px * 16 + tid] =
                psum[0][tid] + psum[1][tid] + psum[2][tid] + psum[3][tid];

        __syncthreads();                 // drain sq stores (vmcnt 0)
        if (tid == 0) {
            __threadfence();             // write back to MALL (device scope)
            atomicAdd(&flags[1], 1u);    // release
        }
        return;
    }

    const int t = item - 1024;           // 0..3071
    const int g3 = t / 3;
    const int p  = t % 3;

    if (p == 2) {
        // ---- value projection: eqF = Wv @ corr + bv (unit g3) ----
        const int b = g3 >> 8;
        const int n = (g3 & 255) * 16 + l15;

        f16x8 cb[4];
#pragma unroll
        for (int ks = 0; ks < 4; ++ks) {
            f16x8 g;
#pragma unroll
            for (int e = 0; e < 8; ++e) {
                const int c = ks * 32 + lg * 8 + e;
                g[e] = (_Float16)corr[((size_t)(b * CH + c)) * NN + n];
            }
            cb[ks] = g;
        }
#pragma unroll
        for (int half = 0; half < 2; ++half) {
            const int ot = wid + half * 4;
            f32x4 acc = {0.f, 0.f, 0.f, 0.f};
#pragma unroll
            for (int ks = 0; ks < 4; ++ks) {
                const float* wv = Wv + (ot * 16 + l15) * CH + ks * 32 + lg * 8;
                f32x4 w0 = *reinterpret_cast<const f32x4*>(wv);
                f32x4 w1 = *reinterpret_cast<const f32x4*>(wv + 4);
                f16x8 f;
#pragma unroll
                for (int e = 0; e < 4; ++e) { f[e] = (_Float16)w0[e]; f[e + 4] = (_Float16)w1[e]; }
                acc = __builtin_amdgcn_mfma_f32_16x16x32_f16(f, cb[ks], acc, 0, 0, 0);
            }
            f32x4 o4;
#pragma unroll
            for (int r = 0; r < 4; ++r) o4[r] = acc[r] + bv[ot * 16 + lg * 4 + r];
            __builtin_nontemporal_store(
                o4, reinterpret_cast<f32x4*>(eqF + ((size_t)(b * NN + n)) * CH + ot * 16 + lg * 4));
        }
        return;
    }

    // ---- gram unit u = 2*g3 + p  (r8 body, steady-state at write floor) ----
    const int u  = g3 * 2 + p;
    const int jb = (u & 7) * 512;
    const int rb = ((u >> 3) & 63) * 64;
    const int b  = u >> 9;

    if (tid == 0) {
        while (__hip_atomic_load(&flags[1], __ATOMIC_ACQUIRE,
                                 __HIP_MEMORY_SCOPE_AGENT) < 1024u)
            __builtin_amdgcn_s_sleep(8);
        __threadfence();                 // acquire: invalidate stale L2 lines
    }
    __syncthreads();

    const int wjb = jb + wid * 128;
    const _Float16* xb  = xbuf + (size_t)b * NN * PC;
    const float*    sqb = sq + (size_t)b * NN;

    const float bs   = -beta[0] * 1.44269504088896f;  // exp(-b*d2)=exp2(bs*d2)
    const float m2bs = -2.f * bs;

    f16x8 bf[8][2];
    float tj[8];
#pragma unroll
    for (int jtf = 0; jtf < 8; ++jtf) {
        const int j = wjb + jtf * 16 + l15;
#pragma unroll
        for (int ks = 0; ks < 2; ++ks)
            bf[jtf][ks] = *reinterpret_cast<const f16x8*>(
                xb + (size_t)j * PC + ks * 32 + lg * 8);
        tj[jtf] = bs * sqb[j];
    }

    for (int sl = 0; sl < 4; ++sl) {
        const int ibase = rb + sl * 16;

        const f16x8 af0 = *reinterpret_cast<const f16x8*>(
            xb + (size_t)(ibase + l15) * PC + lg * 8);
        const f16x8 af1 = *reinterpret_cast<const f16x8*>(
            xb + (size_t)(ibase + l15) * PC + 32 + lg * 8);

        f32x4 acc[8];
#pragma unroll
        for (int jtf = 0; jtf < 8; ++jtf) {
            f32x4 z = {0.f, 0.f, 0.f, 0.f};
            acc[jtf] = __builtin_amdgcn_mfma_f32_16x16x32_f16(af0, bf[jtf][0], z, 0, 0, 0);
        }
#pragma unroll
        for (int jtf = 0; jtf < 8; ++jtf)
            acc[jtf] = __builtin_amdgcn_mfma_f32_16x16x32_f16(af1, bf[jtf][1], acc[jtf], 0, 0, 0);

        const f32x4 sv = *reinterpret_cast<const f32x4*>(sqb + ibase + lg * 4);

#pragma unroll
        for (int jtf = 0; jtf < 8; ++jtf) {
#pragma unroll
            for (int r = 0; r < 4; ++r) {
                const float ti = bs * sv[r];
                float arg = fminf(fmaf(m2bs, acc[jtf][r], ti + tj[jtf]), 0.f);
                ldsT[wid][lg * 4 + r][jtf * 16 + l15] = __builtin_amdgcn_exp2f(arg);
            }
        }

#pragma unroll
        for (int k = 0; k < 8; ++k) {
            const int row = 2 * k + (lane >> 5);
            const int col = (lane & 31) * 4;
            const f32x4 v = *reinterpret_cast<const f32x4*>(&ldsT[wid][row][col]);
            __builtin_nontemporal_store(
                v, reinterpret_cast<f32x4*>(
                       out + ((size_t)(b * NN + ibase + row)) * NN + wjb + col));
        }
    }
}

extern "C" void kernel_launch(void* const* d_in, const int* in_sizes, int n_in,
                              void* d_out, int out_size, void* d_ws, size_t ws_size,
                              hipStream_t stream) {
    const float* pos_bot = (const float*)d_in[0];
    const float* corr    = (const float*)d_in[1];
    const float* Wp      = (const float*)d_in[2];
    const float* bp      = (const float*)d_in[3];
    const float* Wv      = (const float*)d_in[4];
    const float* bv      = (const float*)d_in[5];
    const float* beta    = (const float*)d_in[6];

    float* out = (float*)d_out;                       // kernel [B,N,N]
    float* eqF = out + (size_t)BB * NN * NN;          // equation_F [B,N,128]

    char* ws = (char*)d_ws;
    _Float16*     xbuf  = (_Float16*)ws;
    float*        sq    = (float*)(ws + XBUF_BYTES);
    unsigned int* flags = (unsigned int*)(ws + XBUF_BYTES + SQ_BYTES);

    hipMemsetAsync(flags, 0, 2 * sizeof(unsigned int), stream);

    mega_kernel<<<dim3(4096), 256, 0, stream>>>(
        pos_bot, corr, Wp, bp, Wv, bv, beta, xbuf, sq, eqF, out, flags);
}

// Round 14
// 69.752 us; speedup vs baseline: 4.4317x; 4.4317x over previous
//
#include <hip/hip_runtime.h>
#include <hip/hip_bf16.h>

typedef _Float16 f16x8 __attribute__((ext_vector_type(8)));
typedef _Float16 f16x4 __attribute__((ext_vector_type(4)));
typedef float    f32x4 __attribute__((ext_vector_type(4)));

constexpr int BB = 4;
constexpr int CH = 128;
constexpr int PC = 64;
constexpr int NN = 4096;

// ---------------------------------------------------------------------------
// proj: unchanged r8 body (pos + val in parallel, 2048 blocks).
// ---------------------------------------------------------------------------
__global__ __launch_bounds__(256) void proj_kernel(
    const float* __restrict__ pos_bot,  // [B,64,N]
    const float* __restrict__ corr,     // [B,128,N]
    const float* __restrict__ Wp,       // [64,64]
    const float* __restrict__ bp,       // [64]
    const float* __restrict__ Wv,       // [128,128]
    const float* __restrict__ bv,       // [128]
    _Float16* __restrict__ xbuf,        // [B,N,64]
    float*    __restrict__ sq,          // [B,N]
    float*    __restrict__ eqF)         // [B,N,128]
{
    const int tid  = threadIdx.x;
    const int wid  = tid >> 6;
    const int lane = tid & 63;
    const int l15  = lane & 15;
    const int lg   = lane >> 4;
    const int b    = blockIdx.y & 3;
    const int n    = blockIdx.x * 16 + l15;

    if ((blockIdx.y >> 2) == 0) {
        const int mt = wid;
        f16x8 wf[2], pb[2];
#pragma unroll
        for (int ks = 0; ks < 2; ++ks) {
            const float* wp = Wp + (mt * 16 + l15) * PC + ks * 32 + lg * 8;
            f32x4 w0 = *reinterpret_cast<const f32x4*>(wp);
            f32x4 w1 = *reinterpret_cast<const f32x4*>(wp + 4);
            f16x8 f;
#pragma unroll
            for (int e = 0; e < 4; ++e) { f[e] = (_Float16)w0[e]; f[e + 4] = (_Float16)w1[e]; }
            wf[ks] = f;
            f16x8 g;
#pragma unroll
            for (int e = 0; e < 8; ++e) {
                const int c = ks * 32 + lg * 8 + e;
                g[e] = (_Float16)pos_bot[((size_t)(b * PC + c)) * NN + n];
            }
            pb[ks] = g;
        }

        f32x4 acc = {0.f, 0.f, 0.f, 0.f};
        acc = __builtin_amdgcn_mfma_f32_16x16x32_f16(wf[0], pb[0], acc, 0, 0, 0);
        acc = __builtin_amdgcn_mfma_f32_16x16x32_f16(wf[1], pb[1], acc, 0, 0, 0);

        float partial = 0.f;
        f16x4 h4;
#pragma unroll
        for (int r = 0; r < 4; ++r) {
            const int o = mt * 16 + lg * 4 + r;
            const float v = acc[r] + bp[o];
            const _Float16 h = (_Float16)v;
            h4[r] = h;
            const float hf = (float)h;
            partial = fmaf(hf, hf, partial);
        }
        *reinterpret_cast<f16x4*>(xbuf + ((size_t)(b * NN + n)) * PC + mt * 16 + lg * 4) = h4;

        partial += __shfl_xor(partial, 16);
        partial += __shfl_xor(partial, 32);
        __shared__ float psum[4][16];
        if (lane < 16) psum[wid][l15] = partial;
        __syncthreads();
        if (tid < 16)
            sq[b * NN + blockIdx.x * 16 + tid] =
                psum[0][tid] + psum[1][tid] + psum[2][tid] + psum[3][tid];
        return;
    }

    f16x8 cb[4];
#pragma unroll
    for (int ks = 0; ks < 4; ++ks) {
        f16x8 g;
#pragma unroll
        for (int e = 0; e < 8; ++e) {
            const int c = ks * 32 + lg * 8 + e;
            g[e] = (_Float16)corr[((size_t)(b * CH + c)) * NN + n];
        }
        cb[ks] = g;
    }
#pragma unroll
    for (int half = 0; half < 2; ++half) {
        const int ot = wid + half * 4;
        f32x4 acc = {0.f, 0.f, 0.f, 0.f};
#pragma unroll
        for (int ks = 0; ks < 4; ++ks) {
            const float* wv = Wv + (ot * 16 + l15) * CH + ks * 32 + lg * 8;
            f32x4 w0 = *reinterpret_cast<const f32x4*>(wv);
            f32x4 w1 = *reinterpret_cast<const f32x4*>(wv + 4);
            f16x8 f;
#pragma unroll
            for (int e = 0; e < 4; ++e) { f[e] = (_Float16)w0[e]; f[e + 4] = (_Float16)w1[e]; }
            acc = __builtin_amdgcn_mfma_f32_16x16x32_f16(f, cb[ks], acc, 0, 0, 0);
        }
        f32x4 o4;
#pragma unroll
        for (int r = 0; r < 4; ++r) o4[r] = acc[r] + bv[ot * 16 + lg * 4 + r];
        __builtin_nontemporal_store(
            o4, reinterpret_cast<f32x4*>(eqF + ((size_t)(b * NN + n)) * CH + ot * 16 + lg * 4));
    }
}

// ---------------------------------------------------------------------------
// gram: SINGLE-GENERATION version of r8.
// 1024 blocks = exactly 4 blocks/CU x 256 CU -> one block generation (r8 had
// 2048 blocks = 2 generations, each paying prologue+drain; r12 proved the
// in-block loop re-pass runs at the 6.85 TB/s write floor, so looping inside
// the block instead of launching a second generation removes one full
// prologue/drain cycle). Each block: bf fragments for its 512-col jb loaded
// ONCE, then loops 2 row-strips x 4 slices (identical body to r12's rep
// loop). Zero main-loop barriers, private-LDS transpose, 512 B-contiguous
// full-line NT stores.
// grid (N/512, N/128, B) = (8, 32, 4) = 1024 blocks.
// MFMA layout (r8-verified): acc=mfma(af,bf): i = lg*4+r, j = jtf*16+l15.
// ---------------------------------------------------------------------------
__global__ __launch_bounds__(256) void gram_kernel(
    const _Float16* __restrict__ xbuf,  // [B,N,64]
    const float*    __restrict__ sq,    // [B,N]
    const float*    __restrict__ beta,  // [1]
    float*          __restrict__ out)   // [B,N,N]
{
    const int tid  = threadIdx.x;
    const int wid  = tid >> 6;
    const int lane = tid & 63;
    const int l15  = lane & 15;
    const int lg   = lane >> 4;
    const int b    = blockIdx.z;
    const int jb   = blockIdx.x * 512;
    const int rb0  = blockIdx.y * 128;        // this block covers 128 i-rows
    const int wjb  = jb + wid * 128;          // wave's 128-col range

    const _Float16* xb  = xbuf + (size_t)b * NN * PC;
    const float*    sqb = sq + (size_t)b * NN;

    const float bs   = -beta[0] * 1.44269504088896f;  // exp(-b*d2)=exp2(bs*d2)
    const float m2bs = -2.f * bs;

    // B fragments + tj for this wave's 128 j — loaded ONCE, reused across
    // both row-strip units (prologue amortization; r8 paid this 2x via a
    // second block generation).
    f16x8 bf[8][2];
    float tj[8];
#pragma unroll
    for (int jtf = 0; jtf < 8; ++jtf) {
        const int j = wjb + jtf * 16 + l15;
#pragma unroll
        for (int ks = 0; ks < 2; ++ks)
            bf[jtf][ks] = *reinterpret_cast<const f16x8*>(
                xb + (size_t)j * PC + ks * 32 + lg * 8);
        tj[jtf] = bs * sqb[j];
    }

    __shared__ float lds[4][16][132];   // per-wave private quadrant

    for (int rbh = 0; rbh < 2; ++rbh) {
        const int rb = rb0 + rbh * 64;

        for (int sl = 0; sl < 4; ++sl) {
            const int ibase = rb + sl * 16;

            const f16x8 af0 = *reinterpret_cast<const f16x8*>(
                xb + (size_t)(ibase + l15) * PC + lg * 8);
            const f16x8 af1 = *reinterpret_cast<const f16x8*>(
                xb + (size_t)(ibase + l15) * PC + 32 + lg * 8);

            f32x4 acc[8];
#pragma unroll
            for (int jtf = 0; jtf < 8; ++jtf) {
                f32x4 z = {0.f, 0.f, 0.f, 0.f};
                acc[jtf] = __builtin_amdgcn_mfma_f32_16x16x32_f16(af0, bf[jtf][0], z, 0, 0, 0);
            }
#pragma unroll
            for (int jtf = 0; jtf < 8; ++jtf)
                acc[jtf] = __builtin_amdgcn_mfma_f32_16x16x32_f16(af1, bf[jtf][1], acc[jtf], 0, 0, 0);

            const f32x4 sv = *reinterpret_cast<const f32x4*>(sqb + ibase + lg * 4);

            // transpose into the wave's private LDS quadrant (no cross-wave sync)
#pragma unroll
            for (int jtf = 0; jtf < 8; ++jtf) {
#pragma unroll
                for (int r = 0; r < 4; ++r) {
                    const float ti = bs * sv[r];
                    float arg = fminf(fmaf(m2bs, acc[jtf][r], ti + tj[jtf]), 0.f);
                    lds[wid][lg * 4 + r][jtf * 16 + l15] = __builtin_amdgcn_exp2f(arg);
                }
            }

            // copy-out: 16 rows x 128 cols; each instr = 2 rows x 512 B contig, NT.
#pragma unroll
            for (int k = 0; k < 8; ++k) {
                const int row = 2 * k + (lane >> 5);
                const int col = (lane & 31) * 4;
                const f32x4 v = *reinterpret_cast<const f32x4*>(&lds[wid][row][col]);
                __builtin_nontemporal_store(
                    v, reinterpret_cast<f32x4*>(
                           out + ((size_t)(b * NN + ibase + row)) * NN + wjb + col));
            }
        }
    }
}

extern "C" void kernel_launch(void* const* d_in, const int* in_sizes, int n_in,
                              void* d_out, int out_size, void* d_ws, size_t ws_size,
                              hipStream_t stream) {
    const float* pos_bot = (const float*)d_in[0];
    const float* corr    = (const float*)d_in[1];
    const float* Wp      = (const float*)d_in[2];
    const float* bp      = (const float*)d_in[3];
    const float* Wv      = (const float*)d_in[4];
    const float* bv      = (const float*)d_in[5];
    const float* beta    = (const float*)d_in[6];

    float* out = (float*)d_out;                       // kernel [B,N,N]
    float* eqF = out + (size_t)BB * NN * NN;          // equation_F [B,N,128]

    _Float16* xbuf = (_Float16*)d_ws;                 // 2 MB
    float* sq = (float*)((char*)d_ws + (size_t)BB * NN * PC * sizeof(_Float16));

    proj_kernel<<<dim3(NN / 16, 2 * BB), 256, 0, stream>>>(
        pos_bot, corr, Wp, bp, Wv, bv, xbuf, sq, eqF);

    gram_kernel<<<dim3(NN / 512, NN / 128, BB), 256, 0, stream>>>(
        xbuf, sq, beta, out);
}